// Round 6
// baseline (759.179 us; speedup 1.0000x reference)
//
#include <hip/hip_runtime.h>
#include <stdint.h>

#define T_DIM 256
#define K_DIM 3072
#define N_DIM 3072
#define R_DIM 32
#define KG    48      // K / GROUP
#define NSPLIT 4      // gemm k-splits (partial buffers, no atomics)

#define PQ_BLOCKS 4608   // pack_qw:   N*K/8 / 256
#define QA_BLOCKS 3072   // quant_act: T*KG waves, 4 waves/block
#define LM_BLOCKS 96     // lora_mid:  K/32

typedef __bf16 bf16x8 __attribute__((ext_vector_type(8)));
typedef float  f32x4  __attribute__((ext_vector_type(4)));
typedef unsigned short u16x8 __attribute__((ext_vector_type(8)));

// round-to-nearest-even fp32 -> bf16 (raw ushort)
__device__ __forceinline__ unsigned short f2bf(float f) {
    unsigned u = __builtin_bit_cast(unsigned, f);
    unsigned rounding = 0x7FFFu + ((u >> 16) & 1u);
    return (unsigned short)((u + rounding) >> 16);
}

__device__ __forceinline__ bf16x8 cvt8(const float* p) {
    float4 lo = ((const float4*)p)[0], hi = ((const float4*)p)[1];
    u16x8 u;
    u[0] = f2bf(lo.x); u[1] = f2bf(lo.y); u[2] = f2bf(lo.z); u[3] = f2bf(lo.w);
    u[4] = f2bf(hi.x); u[5] = f2bf(hi.y); u[6] = f2bf(hi.z); u[7] = f2bf(hi.w);
    return __builtin_bit_cast(bf16x8, u);
}

// ---------------- fat prep kernel: pack_qw | quant_act | lora_mid -----------
__global__ __launch_bounds__(256) void prep(
        const int*   __restrict__ qweight,   // [N][K] codes 0..15
        const float* __restrict__ x,         // [T][K]
        const float* __restrict__ lora_down, // [R][K]
        unsigned*       __restrict__ Qp,     // [48][N][8] packed words
        unsigned short* __restrict__ Ap,     // [48][8][256][8] bf16 units
        float*          __restrict__ Lm) {   // [T][R] fp32 (pre-zeroed)
    int blk = blockIdx.x;
    if (blk < PQ_BLOCKS) {
        // ---- pack qweight -> 4-bit nibbles, chunk-major [kt][n][8] ----
        size_t i = (size_t)blk * 256 + threadIdx.x;   // over N*K/8
        const int4* p = (const int4*)(qweight + i * 8);
        int4 a = p[0], b = p[1];
        unsigned w = (unsigned)(a.x & 15)        | ((unsigned)(a.y & 15) << 4)
                   | ((unsigned)(a.z & 15) << 8) | ((unsigned)(a.w & 15) << 12)
                   | ((unsigned)(b.x & 15) << 16)| ((unsigned)(b.y & 15) << 20)
                   | ((unsigned)(b.z & 15) << 24)| ((unsigned)(b.w & 15) << 28);
        unsigned n  = (unsigned)(i / 384);
        unsigned wo = (unsigned)(i % 384);
        unsigned kt = wo >> 3, wi = wo & 7;
        Qp[((size_t)kt * N_DIM + n) * 8 + wi] = w;
    } else if (blk < PQ_BLOCKS + QA_BLOCKS) {
        // ---- per-(token,group) fake-quant -> Ap unit-major ----
        int widx = (blk - PQ_BLOCKS) * 4 + (threadIdx.x >> 6);   // 0..T*KG-1
        int lane = threadIdx.x & 63;
        int t = widx / KG, g = widx % KG;
        float v = x[(size_t)t * K_DIM + g * 64 + lane];
        float a = fabsf(v);
        #pragma unroll
        for (int off = 32; off; off >>= 1) a = fmaxf(a, __shfl_xor(a, off));
        float scale = fmaxf(a / 7.0f, 1e-8f);
        float q = rintf(v / scale);
        q = fminf(fmaxf(q, -8.f), 7.f);
        Ap[(((size_t)g * 8 + (lane >> 3)) * 256 + t) * 8 + (lane & 7)] = f2bf(q * scale);
    } else {
        // ---- lora_mid partial: one 32-wide k-step per block ----
        int kb = blk - PQ_BLOCKS - QA_BLOCKS;
        int lane = threadIdx.x & 63, wv = threadIdx.x >> 6;
        int mrow = lane & 15, quad = lane >> 4;
        int k0 = kb * 32 + quad * 8;
        bf16x8 a[4], b[2];
        #pragma unroll
        for (int mt = 0; mt < 4; ++mt)
            a[mt] = cvt8(x + (size_t)(wv * 64 + mt * 16 + mrow) * K_DIM + k0);
        #pragma unroll
        for (int nt = 0; nt < 2; ++nt)
            b[nt] = cvt8(lora_down + (size_t)(nt * 16 + mrow) * K_DIM + k0);
        f32x4 acc[4][2];
        f32x4 zero = {0.f, 0.f, 0.f, 0.f};
        #pragma unroll
        for (int i = 0; i < 4; ++i) { acc[i][0] = zero; acc[i][1] = zero; }
        #pragma unroll
        for (int mt = 0; mt < 4; ++mt)
            #pragma unroll
            for (int nt = 0; nt < 2; ++nt)
                acc[mt][nt] = __builtin_amdgcn_mfma_f32_16x16x32_bf16(
                    a[mt], b[nt], acc[mt][nt], 0, 0, 0);
        #pragma unroll
        for (int mt = 0; mt < 4; ++mt)
            #pragma unroll
            for (int nt = 0; nt < 2; ++nt)
                #pragma unroll
                for (int r = 0; r < 4; ++r)
                    atomicAdd(&Lm[(size_t)(wv * 64 + mt * 16 + quad * 4 + r) * R_DIM
                                  + nt * 16 + mrow], acc[mt][nt][r]);
    }
}

// ---------------- gemm v2: reg-A from L2, LDS-B dequant, 384 blocks ---------
// grid (48 nblk, 2 mblk, NSPLIT). M-tile 128, N-tile 64, K-chunk 64.
__global__ __launch_bounds__(256) void gemm_main(
        const uint4*    __restrict__ ApU,     // [48][8][256] 16B units
        const unsigned* __restrict__ Qp,      // [48][N][8] packed words
        const float*    __restrict__ wscales, // [N][48]
        const float*    __restrict__ Lm,      // [T][32] fp32
        const float*    __restrict__ lora_up, // [N][32] fp32
        float*          __restrict__ P) {     // [NSPLIT][T][N] fp32 partials
    __shared__ uint4 BsU[2][512];    // [u(8)][n(64)], dbuf: 16 KB
    int nblk  = blockIdx.x;          // 0..47
    int mblk  = blockIdx.y;          // 0..1
    int split = blockIdx.z;          // 0..NSPLIT-1
    int c0 = split * 12;
    int c1 = (split == NSPLIT - 1) ? KG + 1 : c0 + 12;   // last split owns lora tail
    int tid = threadIdx.x;
    int lane = tid & 63, wv = tid >> 6;
    int mrow = lane & 15, quad = lane >> 4;
    int n_row = tid >> 2, seg = tid & 3;
    const int nbase = nblk * 64;
    const int mbase = mblk * 128 + wv * 32;

    f32x4 acc[2][4];
    f32x4 zero = {0.f, 0.f, 0.f, 0.f};
    #pragma unroll
    for (int i = 0; i < 2; ++i)
        #pragma unroll
        for (int j = 0; j < 4; ++j) acc[i][j] = zero;

    uint2 ubc[2];        // distance-2 packed-code prefetch
    float wsr[2];
    bf16x8 af[2][2][2];  // [buf][ks][mt] A fragments (registers)

    const float* wsrow = wscales + (size_t)(nbase + n_row) * KG;

    // A-frag fetch helper indices: unit u = ks*4 + quad, t = mbase + mt*16 + mrow
    #define AFRAG(kt, ks, mt) \
        (*(const bf16x8*)&ApU[(size_t)(kt) * 2048 + ((ks) * 4 + quad) * 256 + \
                              mbase + (mt) * 16 + mrow])

    // prologue
    {
        #pragma unroll
        for (int ks = 0; ks < 2; ++ks)
            #pragma unroll
            for (int mt = 0; mt < 2; ++mt)
                af[0][ks][mt] = AFRAG(c0, ks, mt);
        const unsigned* q0 = Qp + ((size_t)c0 * N_DIM + nbase + n_row) * 8 + seg * 2;
        const unsigned* q1 = Qp + ((size_t)(c0 + 1) * N_DIM + nbase + n_row) * 8 + seg * 2;
        ubc[0] = *(const uint2*)q0;
        ubc[1] = *(const uint2*)q1;
        wsr[0] = wsrow[c0];
        wsr[1] = wsrow[c0 + 1];
    }

    for (int kt = c0; kt < c1; ++kt) {
        int p = (kt - c0) & 1;
        // stage B(kt) -> Bs[p]
        if (kt < KG) {
            float w = wsr[p];
            unsigned u0 = ubc[p].x, u1 = ubc[p].y;
            alignas(16) unsigned short wb[16];
            #pragma unroll
            for (int j = 0; j < 8; ++j)
                wb[j] = f2bf((float)((int)((u0 >> (4 * j)) & 15u) - 8) * w);
            #pragma unroll
            for (int j = 0; j < 8; ++j)
                wb[8 + j] = f2bf((float)((int)((u1 >> (4 * j)) & 15u) - 8) * w);
            const uint4* w2 = (const uint4*)wb;
            BsU[p][(seg * 2 + 0) * 64 + n_row] = w2[0];
            BsU[p][(seg * 2 + 1) * 64 + n_row] = w2[1];
        } else {
            // lora tail: B[n][k] = lora_up[n][k] for k<32, else 0
            alignas(16) unsigned short wb[16];
            if (seg < 2) {
                const float* lu = lora_up + (size_t)(nbase + n_row) * R_DIM + seg * 16;
                #pragma unroll
                for (int j = 0; j < 16; ++j) wb[j] = f2bf(lu[j]);
            } else {
                #pragma unroll
                for (int j = 0; j < 16; ++j) wb[j] = 0;
            }
            const uint4* w2 = (const uint4*)wb;
            BsU[p][(seg * 2 + 0) * 64 + n_row] = w2[0];
            BsU[p][(seg * 2 + 1) * 64 + n_row] = w2[1];
        }
        __syncthreads();
        // prefetch codes (distance 2)
        if (kt + 2 < c1 && kt + 2 < KG) {
            const unsigned* q2 = Qp + ((size_t)(kt + 2) * N_DIM + nbase + n_row) * 8 + seg * 2;
            ubc[p] = *(const uint2*)q2;
            wsr[p] = wsrow[kt + 2];
        }
        // prefetch A fragments (distance 1) into af[p^1]
        if (kt + 1 < c1) {
            if (kt + 1 < KG) {
                #pragma unroll
                for (int ks = 0; ks < 2; ++ks)
                    #pragma unroll
                    for (int mt = 0; mt < 2; ++mt)
                        af[p ^ 1][ks][mt] = AFRAG(kt + 1, ks, mt);
            } else {
                // tail A from fp32 Lm: k = ks*32 + quad*8; real only k<32
                #pragma unroll
                for (int mt = 0; mt < 2; ++mt) {
                    int row = mbase + mt * 16 + mrow;
                    if (quad < 4)
                        af[p ^ 1][0][mt] = cvt8(Lm + (size_t)row * R_DIM + quad * 8);
                    else
                        af[p ^ 1][0][mt] = __builtin_bit_cast(bf16x8, (u16x8)(0));
                    af[p ^ 1][1][mt] = __builtin_bit_cast(bf16x8, (u16x8)(0));
                }
            }
        }
        // MFMA over af[p], Bs[p]
        #pragma unroll
        for (int ks = 0; ks < 2; ++ks) {
            bf16x8 b[4];
            #pragma unroll
            for (int nt = 0; nt < 4; ++nt)
                b[nt] = *(const bf16x8*)&BsU[p][(ks * 4 + quad) * 64 + nt * 16 + mrow];
            #pragma unroll
            for (int mt = 0; mt < 2; ++mt)
                #pragma unroll
                for (int nt = 0; nt < 4; ++nt)
                    acc[mt][nt] = __builtin_amdgcn_mfma_f32_16x16x32_bf16(
                        af[p][ks][mt], b[nt], acc[mt][nt], 0, 0, 0);
        }
    }
    #undef AFRAG
    // epilogue: streamed partial stores
    float* Pp = P + (size_t)split * (T_DIM * N_DIM);
    #pragma unroll
    for (int nt = 0; nt < 4; ++nt) {
        int n = nbase + nt * 16 + mrow;             // C col = lane & 15
        #pragma unroll
        for (int mt = 0; mt < 2; ++mt) {
            int row0 = mblk * 128 + wv * 32 + mt * 16 + quad * 4;
            #pragma unroll
            for (int r = 0; r < 4; ++r)
                Pp[(size_t)(row0 + r) * N_DIM + n] = acc[mt][nt][r];
        }
    }
}

// ---------------- reduce partials + bias -> out -----------------------------
__global__ __launch_bounds__(256) void reduce_out(
        const float4* __restrict__ P, const float* __restrict__ bias,
        float4* __restrict__ out) {
    int i = blockIdx.x * 256 + threadIdx.x;       // over T*N/4
    const int STRIDE = T_DIM * N_DIM / 4;
    float4 s0 = P[i], s1 = P[i + STRIDE], s2 = P[i + 2 * STRIDE], s3 = P[i + 3 * STRIDE];
    float4 bv = *(const float4*)&bias[(i * 4) % N_DIM];
    float4 o;
    o.x = s0.x + s1.x + s2.x + s3.x + bv.x;
    o.y = s0.y + s1.y + s2.y + s3.y + bv.y;
    o.z = s0.z + s1.z + s2.z + s3.z + bv.z;
    o.w = s0.w + s1.w + s2.w + s3.w + bv.w;
    out[i] = o;
}

extern "C" void kernel_launch(void* const* d_in, const int* in_sizes, int n_in,
                              void* d_out, int out_size, void* d_ws, size_t ws_size,
                              hipStream_t stream) {
    const float* x         = (const float*)d_in[0];
    const int*   qweight   = (const int*)d_in[1];
    const float* wscales   = (const float*)d_in[2];
    const float* lora_down = (const float*)d_in[3];
    const float* lora_up   = (const float*)d_in[4];
    const float* bias      = (const float*)d_in[5];

    char* wsp = (char*)d_ws;
    unsigned short* Ap = (unsigned short*)wsp;                 // 48*2048*16 B
    wsp += (size_t)KG * 2048 * 16;
    float* Lm = (float*)wsp;                                   // 256*32*4 B
    wsp += (size_t)T_DIM * R_DIM * 4;
    unsigned* Qp = (unsigned*)wsp;                             // N*K/8*4 B
    wsp += (size_t)N_DIM * (K_DIM / 8) * 4;
    float* P = (float*)wsp;                                    // NSPLIT*T*N*4 B

    hipMemsetAsync(Lm, 0, (size_t)T_DIM * R_DIM * sizeof(float), stream);
    prep<<<PQ_BLOCKS + QA_BLOCKS + LM_BLOCKS, 256, 0, stream>>>(
        qweight, x, lora_down, Qp, Ap, Lm);
    gemm_main<<<dim3(48, 2, NSPLIT), 256, 0, stream>>>(
        (const uint4*)Ap, Qp, wscales, Lm, lora_up, P);
    reduce_out<<<(T_DIM * N_DIM / 4) / 256, 256, 0, stream>>>(
        (const float4*)P, bias, (float4*)d_out);
}

// Round 8
// 117.478 us; speedup vs baseline: 6.4623x; 6.4623x over previous
//
#include <hip/hip_runtime.h>
#include <stdint.h>

#define T_DIM 256
#define K_DIM 3072
#define N_DIM 3072
#define R_DIM 32
#define KG    48      // K / GROUP
#define NSPLIT 4      // gemm k-splits (partial buffers, no atomics)

#define PQ_BLOCKS 4608   // pack_qw:   N*K/8 / 256
#define QA_BLOCKS 3072   // quant_act: T*KG waves, 4 waves/block
#define LM_BLOCKS 96     // lora_mid:  K/32

typedef __bf16 bf16x8 __attribute__((ext_vector_type(8)));
typedef float  f32x4  __attribute__((ext_vector_type(4)));
typedef unsigned short u16x8 __attribute__((ext_vector_type(8)));

// round-to-nearest-even fp32 -> bf16 (raw ushort)
__device__ __forceinline__ unsigned short f2bf(float f) {
    unsigned u = __builtin_bit_cast(unsigned, f);
    unsigned rounding = 0x7FFFu + ((u >> 16) & 1u);
    return (unsigned short)((u + rounding) >> 16);
}

__device__ __forceinline__ bf16x8 cvt8(const float* p) {
    float4 lo = ((const float4*)p)[0], hi = ((const float4*)p)[1];
    u16x8 u;
    u[0] = f2bf(lo.x); u[1] = f2bf(lo.y); u[2] = f2bf(lo.z); u[3] = f2bf(lo.w);
    u[4] = f2bf(hi.x); u[5] = f2bf(hi.y); u[6] = f2bf(hi.z); u[7] = f2bf(hi.w);
    return __builtin_bit_cast(bf16x8, u);
}

// ---------------- fat prep kernel: pack_qw | quant_act | lora_mid -----------
__global__ __launch_bounds__(256) void prep(
        const int*   __restrict__ qweight,   // [N][K] codes 0..15
        const float* __restrict__ x,         // [T][K]
        const float* __restrict__ lora_down, // [R][K]
        unsigned*       __restrict__ Qp,     // [48][N][8] packed words
        unsigned short* __restrict__ Ap,     // [48][8][256][8] bf16 units
        float*          __restrict__ Lm) {   // [T][R] fp32 (pre-zeroed)
    int blk = blockIdx.x;
    if (blk < PQ_BLOCKS) {
        // ---- pack qweight -> 4-bit nibbles, chunk-major [kt][n][8] ----
        size_t i = (size_t)blk * 256 + threadIdx.x;   // over N*K/8
        const int4* p = (const int4*)(qweight + i * 8);
        int4 a = p[0], b = p[1];
        unsigned w = (unsigned)(a.x & 15)        | ((unsigned)(a.y & 15) << 4)
                   | ((unsigned)(a.z & 15) << 8) | ((unsigned)(a.w & 15) << 12)
                   | ((unsigned)(b.x & 15) << 16)| ((unsigned)(b.y & 15) << 20)
                   | ((unsigned)(b.z & 15) << 24)| ((unsigned)(b.w & 15) << 28);
        unsigned n  = (unsigned)(i / 384);
        unsigned wo = (unsigned)(i % 384);
        unsigned kt = wo >> 3, wi = wo & 7;
        Qp[((size_t)kt * N_DIM + n) * 8 + wi] = w;
    } else if (blk < PQ_BLOCKS + QA_BLOCKS) {
        // ---- per-(token,group) fake-quant -> Ap unit-major ----
        int widx = (blk - PQ_BLOCKS) * 4 + (threadIdx.x >> 6);   // 0..T*KG-1
        int lane = threadIdx.x & 63;
        int t = widx / KG, g = widx % KG;
        float v = x[(size_t)t * K_DIM + g * 64 + lane];
        float a = fabsf(v);
        #pragma unroll
        for (int off = 32; off; off >>= 1) a = fmaxf(a, __shfl_xor(a, off));
        float scale = fmaxf(a / 7.0f, 1e-8f);
        float q = rintf(v / scale);
        q = fminf(fmaxf(q, -8.f), 7.f);
        Ap[(((size_t)g * 8 + (lane >> 3)) * 256 + t) * 8 + (lane & 7)] = f2bf(q * scale);
    } else {
        // ---- lora_mid partial: one 32-wide k-step per block ----
        int kb = blk - PQ_BLOCKS - QA_BLOCKS;
        int lane = threadIdx.x & 63, wv = threadIdx.x >> 6;
        int mrow = lane & 15, quad = lane >> 4;
        int k0 = kb * 32 + quad * 8;
        bf16x8 a[4], b[2];
        #pragma unroll
        for (int mt = 0; mt < 4; ++mt)
            a[mt] = cvt8(x + (size_t)(wv * 64 + mt * 16 + mrow) * K_DIM + k0);
        #pragma unroll
        for (int nt = 0; nt < 2; ++nt)
            b[nt] = cvt8(lora_down + (size_t)(nt * 16 + mrow) * K_DIM + k0);
        f32x4 acc[4][2];
        f32x4 zero = {0.f, 0.f, 0.f, 0.f};
        #pragma unroll
        for (int i = 0; i < 4; ++i) { acc[i][0] = zero; acc[i][1] = zero; }
        #pragma unroll
        for (int mt = 0; mt < 4; ++mt)
            #pragma unroll
            for (int nt = 0; nt < 2; ++nt)
                acc[mt][nt] = __builtin_amdgcn_mfma_f32_16x16x32_bf16(
                    a[mt], b[nt], acc[mt][nt], 0, 0, 0);
        #pragma unroll
        for (int mt = 0; mt < 4; ++mt)
            #pragma unroll
            for (int nt = 0; nt < 2; ++nt)
                #pragma unroll
                for (int r = 0; r < 4; ++r)
                    atomicAdd(&Lm[(size_t)(wv * 64 + mt * 16 + quad * 4 + r) * R_DIM
                                  + nt * 16 + mrow], acc[mt][nt][r]);
    }
}

// ---------------- gemm v2c: reg-A from L2, LDS-B dequant, constexpr parity --
// grid (48 nblk, 2 mblk, NSPLIT). M-tile 128, N-tile 64, K-chunk 64.
__global__ __launch_bounds__(256) void gemm_main(
        const uint4*    __restrict__ ApU,     // [48][8][256] 16B units
        const unsigned* __restrict__ Qp,      // [48][N][8] packed words
        const float*    __restrict__ wscales, // [N][48]
        const float*    __restrict__ Lm,      // [T][32] fp32
        const float*    __restrict__ lora_up, // [N][32] fp32
        float*          __restrict__ P) {     // [NSPLIT][T][N] fp32 partials
    __shared__ uint4 BsU[2][512];    // [u(8)][n(64)], dbuf: 16 KB
    int nblk  = blockIdx.x;          // 0..47
    int mblk  = blockIdx.y;          // 0..1
    int split = blockIdx.z;          // 0..NSPLIT-1
    int c0 = split * 12;
    int c1 = (split == NSPLIT - 1) ? KG + 1 : c0 + 12;   // last split owns lora tail
    int tid = threadIdx.x;
    int lane = tid & 63, wv = tid >> 6;
    int mrow = lane & 15, quad = lane >> 4;
    int n_row = tid >> 2, seg = tid & 3;
    const int nbase = nblk * 64;
    const int mbase = mblk * 128 + wv * 32;

    f32x4 acc[2][4];
    f32x4 zero = {0.f, 0.f, 0.f, 0.f};
    #pragma unroll
    for (int i = 0; i < 2; ++i)
        #pragma unroll
        for (int j = 0; j < 4; ++j) acc[i][j] = zero;

    uint2 ubc[2];        // distance-2 packed-code prefetch (constexpr-indexed)
    float wsr[2];
    bf16x8 af[2][2][2];  // [buf][ks][mt] A fragments (constexpr-indexed)

    const float* wsrow = wscales + (size_t)(nbase + n_row) * KG;

    // A-frag: unit u = ks*4 + quad, t = mbase + mt*16 + mrow
    #define AFRAG(kt, ks, mt) \
        (*(const bf16x8*)&ApU[(size_t)(kt) * 2048 + ((ks) * 4 + quad) * 256 + \
                              mbase + (mt) * 16 + mrow])

    // prologue
    {
        #pragma unroll
        for (int ks = 0; ks < 2; ++ks)
            #pragma unroll
            for (int mt = 0; mt < 2; ++mt)
                af[0][ks][mt] = AFRAG(c0, ks, mt);
        const unsigned* q0 = Qp + ((size_t)c0 * N_DIM + nbase + n_row) * 8 + seg * 2;
        const unsigned* q1 = Qp + ((size_t)(c0 + 1) * N_DIM + nbase + n_row) * 8 + seg * 2;
        ubc[0] = *(const uint2*)q0;
        ubc[1] = *(const uint2*)q1;
        wsr[0] = wsrow[c0];
        wsr[1] = wsrow[c0 + 1];
    }

    // one pipeline step at COMPILE-TIME parity PP; local var is kk (NOT kt —
    // naming it kt would shadow the caller's kt and self-initialize: R7 bug)
    #define STEP(PP, KT)                                                          \
    {                                                                             \
        constexpr int p = (PP);                                                   \
        const int kk = (KT);                                                      \
        if (kk < KG) {                                                            \
            float w = wsr[p];                                                     \
            unsigned u0 = ubc[p].x, u1 = ubc[p].y;                                \
            alignas(16) unsigned short wb[16];                                    \
            _Pragma("unroll")                                                     \
            for (int j = 0; j < 8; ++j)                                           \
                wb[j] = f2bf((float)((int)((u0 >> (4 * j)) & 15u) - 8) * w);      \
            _Pragma("unroll")                                                     \
            for (int j = 0; j < 8; ++j)                                           \
                wb[8 + j] = f2bf((float)((int)((u1 >> (4 * j)) & 15u) - 8) * w);  \
            const uint4* w2 = (const uint4*)wb;                                   \
            BsU[p][(seg * 2 + 0) * 64 + n_row] = w2[0];                           \
            BsU[p][(seg * 2 + 1) * 64 + n_row] = w2[1];                           \
        } else {                                                                  \
            alignas(16) unsigned short wb[16];                                    \
            if (seg < 2) {                                                        \
                const float* lu = lora_up + (size_t)(nbase + n_row) * R_DIM + seg * 16; \
                _Pragma("unroll")                                                 \
                for (int j = 0; j < 16; ++j) wb[j] = f2bf(lu[j]);                 \
            } else {                                                              \
                _Pragma("unroll")                                                 \
                for (int j = 0; j < 16; ++j) wb[j] = 0;                           \
            }                                                                     \
            const uint4* w2 = (const uint4*)wb;                                   \
            BsU[p][(seg * 2 + 0) * 64 + n_row] = w2[0];                           \
            BsU[p][(seg * 2 + 1) * 64 + n_row] = w2[1];                           \
        }                                                                         \
        __syncthreads();                                                          \
        if (kk + 2 < c1 && kk + 2 < KG) {                                         \
            const unsigned* q2 = Qp + ((size_t)(kk + 2) * N_DIM + nbase + n_row) * 8 + seg * 2; \
            ubc[p] = *(const uint2*)q2;                                           \
            wsr[p] = wsrow[kk + 2];                                               \
        }                                                                         \
        if (kk + 1 < c1) {                                                        \
            if (kk + 1 < KG) {                                                    \
                _Pragma("unroll")                                                 \
                for (int ks = 0; ks < 2; ++ks)                                    \
                    _Pragma("unroll")                                             \
                    for (int mt = 0; mt < 2; ++mt)                                \
                        af[p ^ 1][ks][mt] = AFRAG(kk + 1, ks, mt);                \
            } else {                                                              \
                _Pragma("unroll")                                                 \
                for (int mt = 0; mt < 2; ++mt) {                                  \
                    int row = mbase + mt * 16 + mrow;                             \
                    if (quad < 4)                                                 \
                        af[p ^ 1][0][mt] = cvt8(Lm + (size_t)row * R_DIM + quad * 8); \
                    else                                                          \
                        af[p ^ 1][0][mt] = __builtin_bit_cast(bf16x8, (u16x8)(0)); \
                    af[p ^ 1][1][mt] = __builtin_bit_cast(bf16x8, (u16x8)(0));    \
                }                                                                 \
            }                                                                     \
        }                                                                         \
        _Pragma("unroll")                                                         \
        for (int ks = 0; ks < 2; ++ks) {                                          \
            bf16x8 b[4];                                                          \
            _Pragma("unroll")                                                     \
            for (int nt = 0; nt < 4; ++nt)                                        \
                b[nt] = *(const bf16x8*)&BsU[p][(ks * 4 + quad) * 64 + nt * 16 + mrow]; \
            _Pragma("unroll")                                                     \
            for (int mt = 0; mt < 2; ++mt)                                        \
                _Pragma("unroll")                                                 \
                for (int nt = 0; nt < 4; ++nt)                                    \
                    acc[mt][nt] = __builtin_amdgcn_mfma_f32_16x16x32_bf16(        \
                        af[p][ks][mt], b[nt], acc[mt][nt], 0, 0, 0);              \
        }                                                                         \
    }

    int kt = c0;
    for (; kt + 1 < c1; kt += 2) {
        STEP(0, kt);
        STEP(1, kt + 1);
    }
    if (kt < c1) STEP(0, kt);    // odd chunk count (last split's lora tail)

    #undef STEP
    #undef AFRAG
    // epilogue: streamed partial stores
    float* Pp = P + (size_t)split * (T_DIM * N_DIM);
    #pragma unroll
    for (int nt = 0; nt < 4; ++nt) {
        int n = nbase + nt * 16 + mrow;             // C col = lane & 15
        #pragma unroll
        for (int mt = 0; mt < 2; ++mt) {
            int row0 = mblk * 128 + wv * 32 + mt * 16 + quad * 4;
            #pragma unroll
            for (int r = 0; r < 4; ++r)
                Pp[(size_t)(row0 + r) * N_DIM + n] = acc[mt][nt][r];
        }
    }
}

// ---------------- reduce partials + bias -> out -----------------------------
__global__ __launch_bounds__(256) void reduce_out(
        const float4* __restrict__ P, const float* __restrict__ bias,
        float4* __restrict__ out) {
    int i = blockIdx.x * 256 + threadIdx.x;       // over T*N/4
    const int STRIDE = T_DIM * N_DIM / 4;
    float4 s0 = P[i], s1 = P[i + STRIDE], s2 = P[i + 2 * STRIDE], s3 = P[i + 3 * STRIDE];
    float4 bv = *(const float4*)&bias[(i * 4) % N_DIM];
    float4 o;
    o.x = s0.x + s1.x + s2.x + s3.x + bv.x;
    o.y = s0.y + s1.y + s2.y + s3.y + bv.y;
    o.z = s0.z + s1.z + s2.z + s3.z + bv.z;
    o.w = s0.w + s1.w + s2.w + s3.w + bv.w;
    out[i] = o;
}

extern "C" void kernel_launch(void* const* d_in, const int* in_sizes, int n_in,
                              void* d_out, int out_size, void* d_ws, size_t ws_size,
                              hipStream_t stream) {
    const float* x         = (const float*)d_in[0];
    const int*   qweight   = (const int*)d_in[1];
    const float* wscales   = (const float*)d_in[2];
    const float* lora_down = (const float*)d_in[3];
    const float* lora_up   = (const float*)d_in[4];
    const float* bias      = (const float*)d_in[5];

    char* wsp = (char*)d_ws;
    unsigned short* Ap = (unsigned short*)wsp;                 // 48*2048*16 B
    wsp += (size_t)KG * 2048 * 16;
    float* Lm = (float*)wsp;                                   // 256*32*4 B
    wsp += (size_t)T_DIM * R_DIM * 4;
    unsigned* Qp = (unsigned*)wsp;                             // N*K/8*4 B
    wsp += (size_t)N_DIM * (K_DIM / 8) * 4;
    float* P = (float*)wsp;                                    // NSPLIT*T*N*4 B

    hipMemsetAsync(Lm, 0, (size_t)T_DIM * R_DIM * sizeof(float), stream);
    prep<<<PQ_BLOCKS + QA_BLOCKS + LM_BLOCKS, 256, 0, stream>>>(
        qweight, x, lora_down, Qp, Ap, Lm);
    gemm_main<<<dim3(48, 2, NSPLIT), 256, 0, stream>>>(
        (const uint4*)Ap, Qp, wscales, Lm, lora_up, P);
    reduce_out<<<(T_DIM * N_DIM / 4) / 256, 256, 0, stream>>>(
        (const float4*)P, bias, (float4*)d_out);
}

// Round 9
// 116.893 us; speedup vs baseline: 6.4946x; 1.0050x over previous
//
#include <hip/hip_runtime.h>
#include <stdint.h>

#define T_DIM 256
#define K_DIM 3072
#define N_DIM 3072
#define R_DIM 32
#define KG    48      // K / GROUP
#define NSPLIT 6      // gemm k-splits (partial buffers, no atomics); 8 chunks each

#define PQ_BLOCKS 4608   // pack_qw:   N*K/8 / 256
#define QA_BLOCKS 3072   // quant_act: T*KG waves, 4 waves/block
#define LM_BLOCKS 96     // lora_mid:  K/32

typedef __bf16 bf16x8 __attribute__((ext_vector_type(8)));
typedef float  f32x4  __attribute__((ext_vector_type(4)));
typedef unsigned short u16x8 __attribute__((ext_vector_type(8)));

// round-to-nearest-even fp32 -> bf16 (raw ushort)
__device__ __forceinline__ unsigned short f2bf(float f) {
    unsigned u = __builtin_bit_cast(unsigned, f);
    unsigned rounding = 0x7FFFu + ((u >> 16) & 1u);
    return (unsigned short)((u + rounding) >> 16);
}

__device__ __forceinline__ bf16x8 cvt8(const float* p) {
    float4 lo = ((const float4*)p)[0], hi = ((const float4*)p)[1];
    u16x8 u;
    u[0] = f2bf(lo.x); u[1] = f2bf(lo.y); u[2] = f2bf(lo.z); u[3] = f2bf(lo.w);
    u[4] = f2bf(hi.x); u[5] = f2bf(hi.y); u[6] = f2bf(hi.z); u[7] = f2bf(hi.w);
    return __builtin_bit_cast(bf16x8, u);
}

// ---------------- fat prep kernel: pack_qw | quant_act | lora_mid -----------
__global__ __launch_bounds__(256) void prep(
        const int*   __restrict__ qweight,   // [N][K] codes 0..15
        const float* __restrict__ x,         // [T][K]
        const float* __restrict__ lora_down, // [R][K]
        unsigned*       __restrict__ Qp,     // [48][N][8] packed words
        unsigned short* __restrict__ Ap,     // [48][8][256][8] bf16 units
        float*          __restrict__ Lm) {   // [T][R] fp32 (pre-zeroed)
    int blk = blockIdx.x;
    if (blk < PQ_BLOCKS) {
        // ---- pack qweight -> 4-bit nibbles, chunk-major [kt][n][8] ----
        size_t i = (size_t)blk * 256 + threadIdx.x;   // over N*K/8
        const int4* p = (const int4*)(qweight + i * 8);
        int4 a = p[0], b = p[1];
        unsigned w = (unsigned)(a.x & 15)        | ((unsigned)(a.y & 15) << 4)
                   | ((unsigned)(a.z & 15) << 8) | ((unsigned)(a.w & 15) << 12)
                   | ((unsigned)(b.x & 15) << 16)| ((unsigned)(b.y & 15) << 20)
                   | ((unsigned)(b.z & 15) << 24)| ((unsigned)(b.w & 15) << 28);
        unsigned n  = (unsigned)(i / 384);
        unsigned wo = (unsigned)(i % 384);
        unsigned kt = wo >> 3, wi = wo & 7;
        Qp[((size_t)kt * N_DIM + n) * 8 + wi] = w;
    } else if (blk < PQ_BLOCKS + QA_BLOCKS) {
        // ---- per-(token,group) fake-quant -> Ap unit-major ----
        int widx = (blk - PQ_BLOCKS) * 4 + (threadIdx.x >> 6);   // 0..T*KG-1
        int lane = threadIdx.x & 63;
        int t = widx / KG, g = widx % KG;
        float v = x[(size_t)t * K_DIM + g * 64 + lane];
        float a = fabsf(v);
        #pragma unroll
        for (int off = 32; off; off >>= 1) a = fmaxf(a, __shfl_xor(a, off));
        float scale = fmaxf(a / 7.0f, 1e-8f);
        float q = rintf(v / scale);
        q = fminf(fmaxf(q, -8.f), 7.f);
        Ap[(((size_t)g * 8 + (lane >> 3)) * 256 + t) * 8 + (lane & 7)] = f2bf(q * scale);
    } else {
        // ---- lora_mid partial: one 32-wide k-step per block ----
        int kb = blk - PQ_BLOCKS - QA_BLOCKS;
        int lane = threadIdx.x & 63, wv = threadIdx.x >> 6;
        int mrow = lane & 15, quad = lane >> 4;
        int k0 = kb * 32 + quad * 8;
        bf16x8 a[4], b[2];
        #pragma unroll
        for (int mt = 0; mt < 4; ++mt)
            a[mt] = cvt8(x + (size_t)(wv * 64 + mt * 16 + mrow) * K_DIM + k0);
        #pragma unroll
        for (int nt = 0; nt < 2; ++nt)
            b[nt] = cvt8(lora_down + (size_t)(nt * 16 + mrow) * K_DIM + k0);
        f32x4 acc[4][2];
        f32x4 zero = {0.f, 0.f, 0.f, 0.f};
        #pragma unroll
        for (int i = 0; i < 4; ++i) { acc[i][0] = zero; acc[i][1] = zero; }
        #pragma unroll
        for (int mt = 0; mt < 4; ++mt)
            #pragma unroll
            for (int nt = 0; nt < 2; ++nt)
                acc[mt][nt] = __builtin_amdgcn_mfma_f32_16x16x32_bf16(
                    a[mt], b[nt], acc[mt][nt], 0, 0, 0);
        #pragma unroll
        for (int mt = 0; mt < 4; ++mt)
            #pragma unroll
            for (int nt = 0; nt < 2; ++nt)
                #pragma unroll
                for (int r = 0; r < 4; ++r)
                    atomicAdd(&Lm[(size_t)(wv * 64 + mt * 16 + quad * 4 + r) * R_DIM
                                  + nt * 16 + mrow], acc[mt][nt][r]);
    }
}

// ---------------- gemm v2d: reg-A from L2, LDS-B dequant, constexpr parity --
// grid (48 nblk, 2 mblk, NSPLIT). M-tile 128, N-tile 64, K-chunk 64.
__global__ __launch_bounds__(256) void gemm_main(
        const uint4*    __restrict__ ApU,     // [48][8][256] 16B units
        const unsigned* __restrict__ Qp,      // [48][N][8] packed words
        const float*    __restrict__ wscales, // [N][48]
        const float*    __restrict__ Lm,      // [T][32] fp32
        const float*    __restrict__ lora_up, // [N][32] fp32
        float*          __restrict__ P) {     // [NSPLIT][T][N] fp32 partials
    __shared__ uint4 BsU[2][512];    // [u(8)][n(64)], dbuf: 16 KB
    int nblk  = blockIdx.x;          // 0..47
    int mblk  = blockIdx.y;          // 0..1
    int split = blockIdx.z;          // 0..NSPLIT-1
    int c0 = split * (KG / NSPLIT);
    int c1 = (split == NSPLIT - 1) ? KG + 1 : c0 + (KG / NSPLIT);  // last owns lora tail
    int tid = threadIdx.x;
    int lane = tid & 63, wv = tid >> 6;
    int mrow = lane & 15, quad = lane >> 4;
    int n_row = tid >> 2, seg = tid & 3;
    const int nbase = nblk * 64;
    const int mbase = mblk * 128 + wv * 32;

    f32x4 acc[2][4];
    f32x4 zero = {0.f, 0.f, 0.f, 0.f};
    #pragma unroll
    for (int i = 0; i < 2; ++i)
        #pragma unroll
        for (int j = 0; j < 4; ++j) acc[i][j] = zero;

    uint2 ubc[2];        // distance-2 packed-code prefetch (constexpr-indexed)
    float wsr[2];
    bf16x8 af[2][2][2];  // [buf][ks][mt] A fragments (constexpr-indexed)

    const float* wsrow = wscales + (size_t)(nbase + n_row) * KG;

    // A-frag: unit u = ks*4 + quad, t = mbase + mt*16 + mrow
    #define AFRAG(kt, ks, mt) \
        (*(const bf16x8*)&ApU[(size_t)(kt) * 2048 + ((ks) * 4 + quad) * 256 + \
                              mbase + (mt) * 16 + mrow])

    // prologue
    {
        #pragma unroll
        for (int ks = 0; ks < 2; ++ks)
            #pragma unroll
            for (int mt = 0; mt < 2; ++mt)
                af[0][ks][mt] = AFRAG(c0, ks, mt);
        const unsigned* q0 = Qp + ((size_t)c0 * N_DIM + nbase + n_row) * 8 + seg * 2;
        const unsigned* q1 = Qp + ((size_t)(c0 + 1) * N_DIM + nbase + n_row) * 8 + seg * 2;
        ubc[0] = *(const uint2*)q0;
        ubc[1] = *(const uint2*)q1;
        wsr[0] = wsrow[c0];
        wsr[1] = wsrow[c0 + 1];
    }

    // one pipeline step at COMPILE-TIME parity PP; local var is kk (NOT kt —
    // naming it kt would shadow the caller's kt and self-initialize: R7 bug)
    #define STEP(PP, KT)                                                          \
    {                                                                             \
        constexpr int p = (PP);                                                   \
        const int kk = (KT);                                                      \
        if (kk < KG) {                                                            \
            float w = wsr[p];                                                     \
            unsigned u0 = ubc[p].x, u1 = ubc[p].y;                                \
            alignas(16) unsigned short wb[16];                                    \
            _Pragma("unroll")                                                     \
            for (int j = 0; j < 8; ++j)                                           \
                wb[j] = f2bf((float)((int)((u0 >> (4 * j)) & 15u) - 8) * w);      \
            _Pragma("unroll")                                                     \
            for (int j = 0; j < 8; ++j)                                           \
                wb[8 + j] = f2bf((float)((int)((u1 >> (4 * j)) & 15u) - 8) * w);  \
            const uint4* w2 = (const uint4*)wb;                                   \
            BsU[p][(seg * 2 + 0) * 64 + n_row] = w2[0];                           \
            BsU[p][(seg * 2 + 1) * 64 + n_row] = w2[1];                           \
        } else {                                                                  \
            alignas(16) unsigned short wb[16];                                    \
            if (seg < 2) {                                                        \
                const float* lu = lora_up + (size_t)(nbase + n_row) * R_DIM + seg * 16; \
                _Pragma("unroll")                                                 \
                for (int j = 0; j < 16; ++j) wb[j] = f2bf(lu[j]);                 \
            } else {                                                              \
                _Pragma("unroll")                                                 \
                for (int j = 0; j < 16; ++j) wb[j] = 0;                           \
            }                                                                     \
            const uint4* w2 = (const uint4*)wb;                                   \
            BsU[p][(seg * 2 + 0) * 64 + n_row] = w2[0];                           \
            BsU[p][(seg * 2 + 1) * 64 + n_row] = w2[1];                           \
        }                                                                         \
        __syncthreads();                                                          \
        if (kk + 2 < c1 && kk + 2 < KG) {                                         \
            const unsigned* q2 = Qp + ((size_t)(kk + 2) * N_DIM + nbase + n_row) * 8 + seg * 2; \
            ubc[p] = *(const uint2*)q2;                                           \
            wsr[p] = wsrow[kk + 2];                                               \
        }                                                                         \
        if (kk + 1 < c1) {                                                        \
            if (kk + 1 < KG) {                                                    \
                _Pragma("unroll")                                                 \
                for (int ks = 0; ks < 2; ++ks)                                    \
                    _Pragma("unroll")                                             \
                    for (int mt = 0; mt < 2; ++mt)                                \
                        af[p ^ 1][ks][mt] = AFRAG(kk + 1, ks, mt);                \
            } else {                                                              \
                _Pragma("unroll")                                                 \
                for (int mt = 0; mt < 2; ++mt) {                                  \
                    int row = mbase + mt * 16 + mrow;                             \
                    if (quad < 4)                                                 \
                        af[p ^ 1][0][mt] = cvt8(Lm + (size_t)row * R_DIM + quad * 8); \
                    else                                                          \
                        af[p ^ 1][0][mt] = __builtin_bit_cast(bf16x8, (u16x8)(0)); \
                    af[p ^ 1][1][mt] = __builtin_bit_cast(bf16x8, (u16x8)(0));    \
                }                                                                 \
            }                                                                     \
        }                                                                         \
        _Pragma("unroll")                                                         \
        for (int ks = 0; ks < 2; ++ks) {                                          \
            bf16x8 b[4];                                                          \
            _Pragma("unroll")                                                     \
            for (int nt = 0; nt < 4; ++nt)                                        \
                b[nt] = *(const bf16x8*)&BsU[p][(ks * 4 + quad) * 64 + nt * 16 + mrow]; \
            _Pragma("unroll")                                                     \
            for (int mt = 0; mt < 2; ++mt)                                        \
                _Pragma("unroll")                                                 \
                for (int nt = 0; nt < 4; ++nt)                                    \
                    acc[mt][nt] = __builtin_amdgcn_mfma_f32_16x16x32_bf16(        \
                        af[p][ks][mt], b[nt], acc[mt][nt], 0, 0, 0);              \
        }                                                                         \
    }

    int kt = c0;
    for (; kt + 1 < c1; kt += 2) {
        STEP(0, kt);
        STEP(1, kt + 1);
    }
    if (kt < c1) STEP(0, kt);    // odd chunk count (last split's lora tail)

    #undef STEP
    #undef AFRAG
    // epilogue: streamed partial stores
    float* Pp = P + (size_t)split * (T_DIM * N_DIM);
    #pragma unroll
    for (int nt = 0; nt < 4; ++nt) {
        int n = nbase + nt * 16 + mrow;             // C col = lane & 15
        #pragma unroll
        for (int mt = 0; mt < 2; ++mt) {
            int row0 = mblk * 128 + wv * 32 + mt * 16 + quad * 4;
            #pragma unroll
            for (int r = 0; r < 4; ++r)
                Pp[(size_t)(row0 + r) * N_DIM + n] = acc[mt][nt][r];
        }
    }
}

// ---------------- reduce partials + bias -> out -----------------------------
__global__ __launch_bounds__(256) void reduce_out(
        const float4* __restrict__ P, const float* __restrict__ bias,
        float4* __restrict__ out) {
    int i = blockIdx.x * 256 + threadIdx.x;       // over T*N/4
    const int STRIDE = T_DIM * N_DIM / 4;
    float4 bv = *(const float4*)&bias[(i * 4) % N_DIM];
    float4 o = bv;
    #pragma unroll
    for (int s = 0; s < NSPLIT; ++s) {
        float4 v = P[i + s * STRIDE];
        o.x += v.x; o.y += v.y; o.z += v.z; o.w += v.w;
    }
    out[i] = o;
}

extern "C" void kernel_launch(void* const* d_in, const int* in_sizes, int n_in,
                              void* d_out, int out_size, void* d_ws, size_t ws_size,
                              hipStream_t stream) {
    const float* x         = (const float*)d_in[0];
    const int*   qweight   = (const int*)d_in[1];
    const float* wscales   = (const float*)d_in[2];
    const float* lora_down = (const float*)d_in[3];
    const float* lora_up   = (const float*)d_in[4];
    const float* bias      = (const float*)d_in[5];

    char* wsp = (char*)d_ws;
    unsigned short* Ap = (unsigned short*)wsp;                 // 48*2048*16 B
    wsp += (size_t)KG * 2048 * 16;
    float* Lm = (float*)wsp;                                   // 256*32*4 B
    wsp += (size_t)T_DIM * R_DIM * 4;
    unsigned* Qp = (unsigned*)wsp;                             // N*K/8*4 B
    wsp += (size_t)N_DIM * (K_DIM / 8) * 4;
    float* P = (float*)wsp;                                    // NSPLIT*T*N*4 B

    hipMemsetAsync(Lm, 0, (size_t)T_DIM * R_DIM * sizeof(float), stream);
    prep<<<PQ_BLOCKS + QA_BLOCKS + LM_BLOCKS, 256, 0, stream>>>(
        qweight, x, lora_down, Qp, Ap, Lm);
    gemm_main<<<dim3(48, 2, NSPLIT), 256, 0, stream>>>(
        (const uint4*)Ap, Qp, wscales, Lm, lora_up, P);
    reduce_out<<<(T_DIM * N_DIM / 4) / 256, 256, 0, stream>>>(
        (const float4*)P, bias, (float4*)d_out);
}